// Round 1
// 11866.199 us; speedup vs baseline: 1.3249x; 1.3249x over previous
//
#include <hip/hip_runtime.h>

// ---------------------------------------------------------------------------
// V4: persistent MFMA LSTM — L2-cached h exchange + distributed flags.
//  - f16 two-plane split (hi/lo), 3 x mfma_f32_16x16x32_f16 per k-tile
//  - hi-plane weights in VGPRs/AGPRs, lo-plane weights in LDS (shared copy)
//  - cross-WG protocol (NEW):
//      producers: write-through h stores (sc0 sc1) -> __syncthreads drains
//                 vmcnt -> per-WG flag store flags[w]=t+1 (relaxed agent).
//      consumers: wave-0 polls all producer flags with 64-lane loads + __all,
//                 then acquire fence at agent scope (buffer_inv: L1+L2) ->
//                 __syncthreads -> h read via NORMAL CACHED loads.
//    h now lives in each XCD's L2 (one MALL fill per XCD per step instead of
//    every WG streaming full h from the coherence point), and the serialized
//    single-counter fetch_add/poll contention is gone.
//  - all global stores everywhere are write-through (agent-scope atomic) so
//    the per-step L2 invalidates can never drop dirty lines.
// ---------------------------------------------------------------------------

constexpr int BB   = 64;
constexpr int TT   = 1024;
constexpr int DIN  = 256;
constexpr int H0   = 512;
constexpr int H1   = 256;
constexpr int NWG0 = 128;
constexpr int NWG1 = 64;
constexpr int NWG  = NWG0 + NWG1;
constexpr int NTHR = 256;
constexpr int NKT  = 24;       // K = 768 = 24 tiles of 32

typedef _Float16 v8h __attribute__((ext_vector_type(8)));
typedef __fp16   v2p __attribute__((ext_vector_type(2)));   // cvt_pkrtz result type
typedef float    v4f __attribute__((ext_vector_type(4)));
typedef unsigned int v4u __attribute__((ext_vector_type(4)));

union U1 { unsigned u; v2p h; };
union U4 { v4u u; v8h h; };

__device__ __forceinline__ unsigned pk2(float a, float b){
  U1 c; c.h = __builtin_amdgcn_cvt_pkrtz(a, b); return c.u;
}
__device__ __forceinline__ float lo16(unsigned u){ U1 c; c.u = u; return (float)c.h[0]; }
__device__ __forceinline__ float hi16(unsigned u){ U1 c; c.u = u; return (float)c.h[1]; }
__device__ __forceinline__ v8h as_h8(v4u u){ U4 c; c.u = u; return c.h; }

__device__ __forceinline__ v4f mfma16(v8h a, v8h b, v4f c){
  return __builtin_amdgcn_mfma_f32_16x16x32_f16(a, b, c, 0, 0, 0);
}

__device__ __forceinline__ float sigf(float v){ return 1.0f / (1.0f + __expf(-v)); }
__device__ __forceinline__ float tanhf_(float v){
  float e = __expf(2.0f * v);
  return 1.0f - 2.0f / (e + 1.0f);     // inf-safe
}

// wave-0 parallel flag wait: all flags[0..n) >= tgt. n is 64 or 128.
// Flags are per-producer words (distinct addresses) -> no same-line atomic
// serialization; one iteration = 1-2 coalesced 64-lane loads + __all.
__device__ __forceinline__ void waitflags(const unsigned* f, int n, unsigned tgt, int lane){
  for (;;){
    bool ok = __hip_atomic_load(f + lane, __ATOMIC_RELAXED, __HIP_MEMORY_SCOPE_AGENT) >= tgt;
    if (n > 64)
      ok = ok && (__hip_atomic_load(f + 64 + lane, __ATOMIC_RELAXED, __HIP_MEMORY_SCOPE_AGENT) >= tgt);
    if (__all(ok)) return;
    __builtin_amdgcn_s_sleep(1);
  }
}

// acquire at agent scope: s_waitcnt + invalidate L1/L2 so subsequent normal
// cached loads refill fresh data from the coherence point.
__device__ __forceinline__ void acq_fence(){
  __builtin_amdgcn_fence(__ATOMIC_ACQUIRE, "agent");
}

// pack two pair-dword quads into hi-plane / lo-plane A fragments
__device__ __forceinline__ void frag_from_pairs(v4u p0, v4u p1, v8h& A, v8h& B){
  v4u ua, ub;
  ua[0] = __builtin_amdgcn_perm(p0[1], p0[0], 0x05040100u);
  ua[1] = __builtin_amdgcn_perm(p0[3], p0[2], 0x05040100u);
  ua[2] = __builtin_amdgcn_perm(p1[1], p1[0], 0x05040100u);
  ua[3] = __builtin_amdgcn_perm(p1[3], p1[2], 0x05040100u);
  ub[0] = __builtin_amdgcn_perm(p0[1], p0[0], 0x07060302u);
  ub[1] = __builtin_amdgcn_perm(p0[3], p0[2], 0x07060302u);
  ub[2] = __builtin_amdgcn_perm(p1[1], p1[0], 0x07060302u);
  ub[3] = __builtin_amdgcn_perm(p1[3], p1[2], 0x07060302u);
  A = as_h8(ua); B = as_h8(ub);
}

__device__ __forceinline__ void frag_from_floats(v4f f0, v4f f1, v8h& A, v8h& B){
  float v[8] = { f0[0], f0[1], f0[2], f0[3], f1[0], f1[1], f1[2], f1[3] };
  v4u ua, ub;
  #pragma unroll
  for (int d = 0; d < 4; ++d){
    unsigned p = pk2(v[2*d], v[2*d+1]);
    ua[d] = p;
    ub[d] = pk2(v[2*d] - lo16(p), v[2*d+1] - hi16(p));
  }
  A = as_h8(ua); B = as_h8(ub);
}

__global__ void __launch_bounds__(NTHR, 1)
lstm_mfma(const float* __restrict__ x, const unsigned* __restrict__ xp, int use_xp,
          const float* __restrict__ Wih0, const float* __restrict__ bih0,
          const float* __restrict__ Whh0, const float* __restrict__ bhh0,
          const float* __restrict__ Wih1, const float* __restrict__ bih1,
          const float* __restrict__ Whh1, const float* __restrict__ bhh1,
          unsigned* h1p, unsigned* h2p,
          unsigned* flg0, unsigned* flg1,
          float* out)
{
  __shared__ v4u wfbs[NKT * 64];       // 24 KB: lo-plane weight B-fragments

  const int tid   = threadIdx.x;
  const int wg    = blockIdx.x;
  const bool isL0 = wg < NWG0;
  const int lw    = isL0 ? wg : wg - NWG0;
  const int H     = isL0 ? H0 : H1;
  const int jbase = lw * 4;            // 4 h-cols per WG
  const int lane  = tid & 63;
  const int mt    = tid >> 6;          // wave id = m-tile (16 batches)
  const int n     = lane & 15;         // MFMA n-index / A row-in-tile
  const int quad  = lane >> 4;
  // n -> gate (n>>2 in {i,f,g,o}), h-col jbase + (n&3)
  const int gcol  = (n >> 2) * H + jbase + (n & 3);
  const int brow  = mt * 16 + n;       // batch row this lane loads for A

  // ---- prologue: gather weight B-fragments; hi-plane -> VGPRs, lo -> LDS ----
  v4u wfa[NKT];
  {
    const float* Wi = isL0 ? Wih0 : Wih1;
    const float* Wh = isL0 ? Whh0 : Whh1;
    const int Ki  = isL0 ? DIN : H0;
    const int ldw = 4 * H;
    #pragma unroll
    for (int kt = 0; kt < NKT; ++kt){
      const int ks = kt * 32 + quad * 8;
      float w[8];
      #pragma unroll
      for (int j = 0; j < 8; ++j){
        const int k = ks + j;
        w[j] = (k < Ki) ? Wi[(size_t)k * ldw + gcol]
                        : Wh[(size_t)(k - Ki) * ldw + gcol];
      }
      v4u ua, ub;
      #pragma unroll
      for (int d = 0; d < 4; ++d){
        const unsigned p = pk2(w[2*d], w[2*d+1]);
        ua[d] = p;
        ub[d] = pk2(w[2*d] - lo16(p), w[2*d+1] - hi16(p));
      }
      wfa[kt] = ua;
      if (mt == 0) wfbs[kt * 64 + lane] = ub;   // fragments identical across waves
    }
  }
  const float bsum = isL0 ? (bih0[gcol] + bhh0[gcol]) : (bih1[gcol] + bhh1[gcol]);

  float c0 = 0.f, c1 = 0.f, c2 = 0.f, c3 = 0.f;   // cell state (lanes n<4)
  __syncthreads();

  for (int t = 0; t < TT; ++t){
    v4f acc1 = { bsum, bsum, bsum, bsum };
    v4f acc2 = { 0.f, 0.f, 0.f, 0.f };

    if (isL0){
      // ---- x-part first: no cross-WG dependency, hides the flag wait ----
      if (use_xp){
        const unsigned* xr = xp + ((size_t)brow * TT + t) * DIN + quad * 8;
        #pragma unroll
        for (int kt = 0; kt < 8; ++kt){
          v4u p0 = *(const v4u*)(xr + kt * 32);
          v4u p1 = *(const v4u*)(xr + kt * 32 + 4);
          v8h A, Ab; frag_from_pairs(p0, p1, A, Ab);
          v8h Wa = as_h8(wfa[kt]), Wb = as_h8(wfbs[kt * 64 + lane]);
          acc1 = mfma16(A,  Wa, acc1);
          acc2 = mfma16(A,  Wb, acc2);
          acc2 = mfma16(Ab, Wa, acc2);
        }
      } else {
        const float* xr = x + ((size_t)brow * TT + t) * DIN + quad * 8;
        #pragma unroll
        for (int kt = 0; kt < 8; ++kt){
          v4f f0 = *(const v4f*)(xr + kt * 32);
          v4f f1 = *(const v4f*)(xr + kt * 32 + 4);
          v8h A, Ab; frag_from_floats(f0, f1, A, Ab);
          v8h Wa = as_h8(wfa[kt]), Wb = as_h8(wfbs[kt * 64 + lane]);
          acc1 = mfma16(A,  Wa, acc1);
          acc2 = mfma16(A,  Wb, acc2);
          acc2 = mfma16(Ab, Wa, acc2);
        }
      }
      // ---- wait for h1(t-1): all L0 flags >= t, then invalidate caches ----
      if (tid < 64){
        if (t >= 1) waitflags(flg0, NWG0, (unsigned)t, tid);
        acq_fence();
      }
      __syncthreads();
      // ---- h1(t-1) part, slot (t+1)&1, NORMAL cached loads (L2-shared) ----
      const unsigned* hr = h1p + (size_t)((t + 1) & 1) * (BB * H0)
                               + (size_t)brow * H0 + quad * 8;
      #pragma unroll
      for (int kt = 0; kt < 16; ++kt){
        v4u p0 = *(const v4u*)(hr + kt * 32);
        v4u p1 = *(const v4u*)(hr + kt * 32 + 4);
        v8h A, Ab; frag_from_pairs(p0, p1, A, Ab);
        v8h Wa = as_h8(wfa[kt + 8]), Wb = as_h8(wfbs[(kt + 8) * 64 + lane]);
        acc1 = mfma16(A,  Wa, acc1);
        acc2 = mfma16(A,  Wb, acc2);
        acc2 = mfma16(Ab, Wa, acc2);
      }
      // ---- slot-free guard before storing h1(t) over h1(t-2): L1 done t-2 ----
      if (tid < 64 && t >= 2) waitflags(flg1, NWG1, (unsigned)(t - 1), tid);
      __syncthreads();
    } else {
      // ---- h2(t-1) part first: own-layer dep, usually ready ----
      if (tid < 64){
        if (t >= 1) waitflags(flg1, NWG1, (unsigned)t, tid);
        acq_fence();
      }
      __syncthreads();
      const unsigned* h2r = h2p + (size_t)((t + 1) & 1) * (BB * H1)
                                + (size_t)brow * H1 + quad * 8;
      #pragma unroll
      for (int kt = 0; kt < 8; ++kt){
        v4u p0 = *(const v4u*)(h2r + kt * 32);
        v4u p1 = *(const v4u*)(h2r + kt * 32 + 4);
        v8h A, Ab; frag_from_pairs(p0, p1, A, Ab);
        v8h Wa = as_h8(wfa[kt + 16]), Wb = as_h8(wfbs[(kt + 16) * 64 + lane]);
        acc1 = mfma16(A,  Wa, acc1);
        acc2 = mfma16(A,  Wb, acc2);
        acc2 = mfma16(Ab, Wa, acc2);
      }
      // ---- wait for h1(t): all L0 flags >= t+1, then invalidate caches ----
      if (tid < 64){
        waitflags(flg0, NWG0, (unsigned)(t + 1), tid);
        acq_fence();
      }
      __syncthreads();
      const unsigned* hr = h1p + (size_t)(t & 1) * (BB * H0)
                               + (size_t)brow * H0 + quad * 8;
      #pragma unroll
      for (int kt = 0; kt < 16; ++kt){
        v4u p0 = *(const v4u*)(hr + kt * 32);
        v4u p1 = *(const v4u*)(hr + kt * 32 + 4);
        v8h A, Ab; frag_from_pairs(p0, p1, A, Ab);
        v8h Wa = as_h8(wfa[kt]), Wb = as_h8(wfbs[kt * 64 + lane]);
        acc1 = mfma16(A,  Wa, acc1);
        acc2 = mfma16(A,  Wb, acc2);
        acc2 = mfma16(Ab, Wa, acc2);
      }
    }

    // ---- elementwise LSTM: gather (i,f,g,o) per (b, h-col) via shfl_xor ----
    v4f gv = acc1 + acc2;
    float pv0 = __shfl_xor(gv[0], 4), pv1 = __shfl_xor(gv[1], 4),
          pv2 = __shfl_xor(gv[2], 4), pv3 = __shfl_xor(gv[3], 4);
    float qv0 = __shfl_xor(gv[0], 8), qv1 = __shfl_xor(gv[1], 8),
          qv2 = __shfl_xor(gv[2], 8), qv3 = __shfl_xor(gv[3], 8);
    float sv0 = __shfl_xor(pv0, 8), sv1 = __shfl_xor(pv1, 8),
          sv2 = __shfl_xor(pv2, 8), sv3 = __shfl_xor(pv3, 8);

    if (n < 4){
      // lane n<4: i = gv, f = pv, g = qv, o = sv ; rows b = mt*16 + quad*4 + r
      float iv[4] = { gv[0], gv[1], gv[2], gv[3] };
      float fv[4] = { pv0, pv1, pv2, pv3 };
      float gg[4] = { qv0, qv1, qv2, qv3 };
      float ov[4] = { sv0, sv1, sv2, sv3 };
      float cc[4] = { c0, c1, c2, c3 };
      const int col = jbase + n;
      #pragma unroll
      for (int r = 0; r < 4; ++r){
        float cn = sigf(fv[r]) * cc[r] + sigf(iv[r]) * tanhf_(gg[r]);
        float hn = sigf(ov[r]) * tanhf_(cn);
        cc[r] = cn;
        const int b = mt * 16 + quad * 4 + r;
        unsigned pa = pk2(hn, 0.f);
        unsigned pd = pk2(hn, hn - lo16(pa));
        if (isL0){
          __hip_atomic_store(h1p + (size_t)(t & 1) * (BB * H0) + (size_t)b * H0 + col,
                             pd, __ATOMIC_RELAXED, __HIP_MEMORY_SCOPE_AGENT);
        } else {
          __hip_atomic_store(h2p + (size_t)(t & 1) * (BB * H1) + (size_t)b * H1 + col,
                             pd, __ATOMIC_RELAXED, __HIP_MEMORY_SCOPE_AGENT);
          // write-through so per-step L2 invalidates never see a dirty line
          __hip_atomic_store(out + ((size_t)b * TT + t) * H1 + col, hn,
                             __ATOMIC_RELAXED, __HIP_MEMORY_SCOPE_AGENT);
        }
      }
      c0 = cc[0]; c1 = cc[1]; c2 = cc[2]; c3 = cc[3];
    }

    // ---- publish: barrier drains vmcnt (write-through stores are at the
    // coherence point once retired) -> per-WG relaxed flag store suffices ----
    __syncthreads();
    if (tid == 0){
      __hip_atomic_store(isL0 ? (flg0 + lw) : (flg1 + lw), (unsigned)(t + 1),
                         __ATOMIC_RELAXED, __HIP_MEMORY_SCOPE_AGENT);
    }
  }
}

__global__ void init_ws(unsigned* ws, int nz){
  int i = blockIdx.x * blockDim.x + threadIdx.x;
  if (i < nz)
    __hip_atomic_store(ws + i, 0u, __ATOMIC_RELAXED, __HIP_MEMORY_SCOPE_AGENT);
}

__global__ void conv_x(const float4* __restrict__ x4,
                       unsigned long long* __restrict__ xp2, int n4){
  int i = blockIdx.x * blockDim.x + threadIdx.x;
  if (i >= n4) return;
  float4 f = x4[i];
  float v[4] = { f.x, f.y, f.z, f.w };
  unsigned o[4];
  #pragma unroll
  for (int d = 0; d < 4; ++d){
    unsigned p = pk2(v[d], 0.f);
    o[d] = pk2(v[d], v[d] - lo16(p));
  }
  unsigned long long lo = (unsigned long long)o[0] | ((unsigned long long)o[1] << 32);
  unsigned long long hi = (unsigned long long)o[2] | ((unsigned long long)o[3] << 32);
  // write-through: no dirty L2 lines to be lost by lstm_mfma's invalidates
  __hip_atomic_store(xp2 + 2 * i + 0, lo, __ATOMIC_RELAXED, __HIP_MEMORY_SCOPE_AGENT);
  __hip_atomic_store(xp2 + 2 * i + 1, hi, __ATOMIC_RELAXED, __HIP_MEMORY_SCOPE_AGENT);
}

extern "C" void kernel_launch(void* const* d_in, const int* in_sizes, int n_in,
                              void* d_out, int out_size, void* d_ws, size_t ws_size,
                              hipStream_t stream) {
  const float* x    = (const float*)d_in[0];
  const float* Wih0 = (const float*)d_in[1];
  const float* bih0 = (const float*)d_in[2];
  const float* Whh0 = (const float*)d_in[3];
  const float* bhh0 = (const float*)d_in[4];
  const float* Wih1 = (const float*)d_in[5];
  const float* bih1 = (const float*)d_in[6];
  const float* Whh1 = (const float*)d_in[7];
  const float* bhh1 = (const float*)d_in[8];
  float* outp = (float*)d_out;

  unsigned* ws   = (unsigned*)d_ws;
  unsigned* h1p  = ws;                       // 2*64*512  = 65536 dwords
  unsigned* h2p  = h1p + 2 * BB * H0;        // 2*64*256  = 32768
  unsigned* flg0 = h2p + 2 * BB * H1;        // region sized TT dwords (uses 128)
  unsigned* flg1 = flg0 + TT;                // region sized TT dwords (uses 64)
  unsigned* xp   = flg1 + TT;                // optional: B*T*DIN pair dwords
  const int nz = 2 * BB * H0 + 2 * BB * H1 + 2 * TT;   // dwords to zero

  const size_t need_xp = ((size_t)nz + (size_t)BB * TT * DIN) * 4;
  int use_xp = (ws_size >= need_xp) ? 1 : 0;

  init_ws<<<dim3((nz + 255) / 256), dim3(256), 0, stream>>>(ws, nz);
  if (use_xp){
    const int n4 = BB * TT * DIN / 4;
    conv_x<<<dim3((n4 + 255) / 256), dim3(256), 0, stream>>>(
        (const float4*)x, (unsigned long long*)xp, n4);
  }

  lstm_mfma<<<dim3(NWG), dim3(NTHR), 0, stream>>>(
      x, xp, use_xp,
      Wih0, bih0, Whh0, bhh0,
      Wih1, bih1, Whh1, bhh1,
      h1p, h2p, flg0, flg1, outp);
}

// Round 2
// 10340.792 us; speedup vs baseline: 1.5204x; 1.1475x over previous
//
#include <hip/hip_runtime.h>

// ---------------------------------------------------------------------------
// V5: persistent MFMA LSTM — skewed two-layer pipeline, ONE global sync/step.
//  - f16 two-plane split (hi/lo), 3 x mfma_f32_16x16x32_f16 per k-tile
//  - hi-plane weights in VGPRs, lo-plane weights in LDS (shared copy)
//  - NEW schedule: at iteration i, L0 WGs compute h1(i)=f(x(i),h1(i-1)) and
//    L1 WGs compute h2(i-1)=f(h1(i-1),h2(i-2)).  Every cross-WG input was
//    published before the single combined barrier at the top of iteration i,
//    so the 2-3 serialized wait/fence/refill hops per step of V4 collapse to
//    exactly one: poll 192 per-WG flags >= i, one acquire fence, done.
//    V4's slot-free guard folds into the same barrier (readers of the slot
//    being overwritten all ran in iteration i-1, covered by flags >= i).
//  - release side unchanged (verified): write-through h stores (sc0 sc1) ->
//    __syncthreads drains vmcnt -> per-WG relaxed flag store.
//  - acquire side unchanged (verified): wave-0 polls flags, agent acquire
//    fence (L1/L2 invalidate), __syncthreads, normal cached h loads.
// ---------------------------------------------------------------------------

constexpr int BB   = 64;
constexpr int TT   = 1024;
constexpr int DIN  = 256;
constexpr int H0   = 512;
constexpr int H1   = 256;
constexpr int NWG0 = 128;
constexpr int NWG1 = 64;
constexpr int NWG  = NWG0 + NWG1;
constexpr int NTHR = 256;
constexpr int NKT  = 24;       // K = 768 = 24 tiles of 32

typedef _Float16 v8h __attribute__((ext_vector_type(8)));
typedef __fp16   v2p __attribute__((ext_vector_type(2)));   // cvt_pkrtz result type
typedef float    v4f __attribute__((ext_vector_type(4)));
typedef unsigned int v4u __attribute__((ext_vector_type(4)));

union U1 { unsigned u; v2p h; };
union U4 { v4u u; v8h h; };

__device__ __forceinline__ unsigned pk2(float a, float b){
  U1 c; c.h = __builtin_amdgcn_cvt_pkrtz(a, b); return c.u;
}
__device__ __forceinline__ float lo16(unsigned u){ U1 c; c.u = u; return (float)c.h[0]; }
__device__ __forceinline__ float hi16(unsigned u){ U1 c; c.u = u; return (float)c.h[1]; }
__device__ __forceinline__ v8h as_h8(v4u u){ U4 c; c.u = u; return c.h; }

__device__ __forceinline__ v4f mfma16(v8h a, v8h b, v4f c){
  return __builtin_amdgcn_mfma_f32_16x16x32_f16(a, b, c, 0, 0, 0);
}

__device__ __forceinline__ float sigf(float v){ return 1.0f / (1.0f + __expf(-v)); }
__device__ __forceinline__ float tanhf_(float v){
  float e = __expf(2.0f * v);
  return 1.0f - 2.0f / (e + 1.0f);     // inf-safe
}

// wave-0 parallel flag wait: all flags[0..n) >= tgt (n multiple of 64).
// Per-producer flag words (distinct addresses) -> no same-line serialization;
// one iteration = n/64 coalesced 64-lane loads + __all.
__device__ __forceinline__ void waitflags(const unsigned* f, int n, unsigned tgt, int lane){
  for (;;){
    bool ok = true;
    #pragma unroll
    for (int base = 0; base < n; base += 64)
      ok = ok && (__hip_atomic_load(f + base + lane, __ATOMIC_RELAXED,
                                    __HIP_MEMORY_SCOPE_AGENT) >= tgt);
    if (__all(ok)) return;
    __builtin_amdgcn_s_sleep(1);
  }
}

// acquire at agent scope: s_waitcnt + invalidate L1/L2 so subsequent normal
// cached loads refill fresh data from the coherence point.
__device__ __forceinline__ void acq_fence(){
  __builtin_amdgcn_fence(__ATOMIC_ACQUIRE, "agent");
}

// pack two pair-dword quads into hi-plane / lo-plane A fragments
__device__ __forceinline__ void frag_from_pairs(v4u p0, v4u p1, v8h& A, v8h& B){
  v4u ua, ub;
  ua[0] = __builtin_amdgcn_perm(p0[1], p0[0], 0x05040100u);
  ua[1] = __builtin_amdgcn_perm(p0[3], p0[2], 0x05040100u);
  ua[2] = __builtin_amdgcn_perm(p1[1], p1[0], 0x05040100u);
  ua[3] = __builtin_amdgcn_perm(p1[3], p1[2], 0x05040100u);
  ub[0] = __builtin_amdgcn_perm(p0[1], p0[0], 0x07060302u);
  ub[1] = __builtin_amdgcn_perm(p0[3], p0[2], 0x07060302u);
  ub[2] = __builtin_amdgcn_perm(p1[1], p1[0], 0x07060302u);
  ub[3] = __builtin_amdgcn_perm(p1[3], p1[2], 0x07060302u);
  A = as_h8(ua); B = as_h8(ub);
}

__device__ __forceinline__ void frag_from_floats(v4f f0, v4f f1, v8h& A, v8h& B){
  float v[8] = { f0[0], f0[1], f0[2], f0[3], f1[0], f1[1], f1[2], f1[3] };
  v4u ua, ub;
  #pragma unroll
  for (int d = 0; d < 4; ++d){
    unsigned p = pk2(v[2*d], v[2*d+1]);
    ua[d] = p;
    ub[d] = pk2(v[2*d] - lo16(p), v[2*d+1] - hi16(p));
  }
  A = as_h8(ua); B = as_h8(ub);
}

__global__ void __launch_bounds__(NTHR, 1)
lstm_mfma(const float* __restrict__ x, const unsigned* __restrict__ xp, int use_xp,
          const float* __restrict__ Wih0, const float* __restrict__ bih0,
          const float* __restrict__ Whh0, const float* __restrict__ bhh0,
          const float* __restrict__ Wih1, const float* __restrict__ bih1,
          const float* __restrict__ Whh1, const float* __restrict__ bhh1,
          unsigned* h1p, unsigned* h2p,
          unsigned* flg, float* out)
{
  __shared__ v4u wfbs[NKT * 64];       // 24 KB: lo-plane weight B-fragments

  const int tid   = threadIdx.x;
  const int wg    = blockIdx.x;
  const bool isL0 = wg < NWG0;
  const int lw    = isL0 ? wg : wg - NWG0;
  const int H     = isL0 ? H0 : H1;
  const int jbase = lw * 4;            // 4 h-cols per WG
  const int lane  = tid & 63;
  const int mt    = tid >> 6;          // wave id = m-tile (16 batches)
  const int n     = lane & 15;         // MFMA n-index / A row-in-tile
  const int quad  = lane >> 4;
  // n -> gate (n>>2 in {i,f,g,o}), h-col jbase + (n&3)
  const int gcol  = (n >> 2) * H + jbase + (n & 3);
  const int brow  = mt * 16 + n;       // batch row this lane loads for A

  // ---- prologue: gather weight B-fragments; hi-plane -> VGPRs, lo -> LDS ----
  v4u wfa[NKT];
  {
    const float* Wi = isL0 ? Wih0 : Wih1;
    const float* Wh = isL0 ? Whh0 : Whh1;
    const int Ki  = isL0 ? DIN : H0;
    const int ldw = 4 * H;
    #pragma unroll
    for (int kt = 0; kt < NKT; ++kt){
      const int ks = kt * 32 + quad * 8;
      float w[8];
      #pragma unroll
      for (int j = 0; j < 8; ++j){
        const int k = ks + j;
        w[j] = (k < Ki) ? Wi[(size_t)k * ldw + gcol]
                        : Wh[(size_t)(k - Ki) * ldw + gcol];
      }
      v4u ua, ub;
      #pragma unroll
      for (int d = 0; d < 4; ++d){
        const unsigned p = pk2(w[2*d], w[2*d+1]);
        ua[d] = p;
        ub[d] = pk2(w[2*d] - lo16(p), w[2*d+1] - hi16(p));
      }
      wfa[kt] = ua;
      if (mt == 0) wfbs[kt * 64 + lane] = ub;   // fragments identical across waves
    }
  }
  const float bsum = isL0 ? (bih0[gcol] + bhh0[gcol]) : (bih1[gcol] + bhh1[gcol]);

  float c0 = 0.f, c1 = 0.f, c2 = 0.f, c3 = 0.f;   // cell state (lanes n<4)
  __syncthreads();

  // iteration i: L0 computes h1(i) (for i < TT); L1 computes h2(i-1) (i >= 1)
  for (int i = 0; i <= TT; ++i){
    const bool act = isL0 ? (i < TT) : (i >= 1);
    const int t    = isL0 ? i : (i - 1);          // this WG's time index

    v4f acc1 = { bsum, bsum, bsum, bsum };
    v4f acc2 = { 0.f, 0.f, 0.f, 0.f };

    // ---- L0 x-part: no cross-WG dependency, runs before/through the wait ----
    if (isL0 && act){
      if (use_xp){
        const unsigned* xr = xp + ((size_t)brow * TT + t) * DIN + quad * 8;
        #pragma unroll
        for (int kt = 0; kt < 8; ++kt){
          v4u p0 = *(const v4u*)(xr + kt * 32);
          v4u p1 = *(const v4u*)(xr + kt * 32 + 4);
          v8h A, Ab; frag_from_pairs(p0, p1, A, Ab);
          v8h Wa = as_h8(wfa[kt]), Wb = as_h8(wfbs[kt * 64 + lane]);
          acc1 = mfma16(A,  Wa, acc1);
          acc2 = mfma16(A,  Wb, acc2);
          acc2 = mfma16(Ab, Wa, acc2);
        }
      } else {
        const float* xr = x + ((size_t)brow * TT + t) * DIN + quad * 8;
        #pragma unroll
        for (int kt = 0; kt < 8; ++kt){
          v4f f0 = *(const v4f*)(xr + kt * 32);
          v4f f1 = *(const v4f*)(xr + kt * 32 + 4);
          v8h A, Ab; frag_from_floats(f0, f1, A, Ab);
          v8h Wa = as_h8(wfa[kt]), Wb = as_h8(wfbs[kt * 64 + lane]);
          acc1 = mfma16(A,  Wa, acc1);
          acc2 = mfma16(A,  Wb, acc2);
          acc2 = mfma16(Ab, Wa, acc2);
        }
      }
    }

    // ---- the single global sync: all WGs finished iteration i-1 ----
    if (tid < 64){
      if (i >= 1) waitflags(flg, NWG, (unsigned)i, lane);
      acq_fence();          // unconditional: also guards graph-replay staleness
    }
    __syncthreads();

    if (act){
      if (isL0){
        // ---- h1(t-1) part, slot (t+1)&1, normal cached loads (L2-shared) ----
        const unsigned* hr = h1p + (size_t)((t + 1) & 1) * (BB * H0)
                                 + (size_t)brow * H0 + quad * 8;
        #pragma unroll
        for (int kt = 0; kt < 16; ++kt){
          v4u p0 = *(const v4u*)(hr + kt * 32);
          v4u p1 = *(const v4u*)(hr + kt * 32 + 4);
          v8h A, Ab; frag_from_pairs(p0, p1, A, Ab);
          v8h Wa = as_h8(wfa[kt + 8]), Wb = as_h8(wfbs[(kt + 8) * 64 + lane]);
          acc1 = mfma16(A,  Wa, acc1);
          acc2 = mfma16(A,  Wb, acc2);
          acc2 = mfma16(Ab, Wa, acc2);
        }
      } else {
        // ---- h2(t-1) part, slot (t+1)&1 ----
        const unsigned* h2r = h2p + (size_t)((t + 1) & 1) * (BB * H1)
                                  + (size_t)brow * H1 + quad * 8;
        #pragma unroll
        for (int kt = 0; kt < 8; ++kt){
          v4u p0 = *(const v4u*)(h2r + kt * 32);
          v4u p1 = *(const v4u*)(h2r + kt * 32 + 4);
          v8h A, Ab; frag_from_pairs(p0, p1, A, Ab);
          v8h Wa = as_h8(wfa[kt + 16]), Wb = as_h8(wfbs[(kt + 16) * 64 + lane]);
          acc1 = mfma16(A,  Wa, acc1);
          acc2 = mfma16(A,  Wb, acc2);
          acc2 = mfma16(Ab, Wa, acc2);
        }
        // ---- h1(t) part, slot t&1 (published before this iteration's barrier) ----
        const unsigned* hr = h1p + (size_t)(t & 1) * (BB * H0)
                                 + (size_t)brow * H0 + quad * 8;
        #pragma unroll
        for (int kt = 0; kt < 16; ++kt){
          v4u p0 = *(const v4u*)(hr + kt * 32);
          v4u p1 = *(const v4u*)(hr + kt * 32 + 4);
          v8h A, Ab; frag_from_pairs(p0, p1, A, Ab);
          v8h Wa = as_h8(wfa[kt]), Wb = as_h8(wfbs[kt * 64 + lane]);
          acc1 = mfma16(A,  Wa, acc1);
          acc2 = mfma16(A,  Wb, acc2);
          acc2 = mfma16(Ab, Wa, acc2);
        }
      }

      // ---- elementwise LSTM: gather (i,f,g,o) per (b, h-col) via shfl_xor ----
      v4f gv = acc1 + acc2;
      float pv0 = __shfl_xor(gv[0], 4), pv1 = __shfl_xor(gv[1], 4),
            pv2 = __shfl_xor(gv[2], 4), pv3 = __shfl_xor(gv[3], 4);
      float qv0 = __shfl_xor(gv[0], 8), qv1 = __shfl_xor(gv[1], 8),
            qv2 = __shfl_xor(gv[2], 8), qv3 = __shfl_xor(gv[3], 8);
      float sv0 = __shfl_xor(pv0, 8), sv1 = __shfl_xor(pv1, 8),
            sv2 = __shfl_xor(pv2, 8), sv3 = __shfl_xor(pv3, 8);

      if (n < 4){
        // lane n<4: i = gv, f = pv, g = qv, o = sv ; rows b = mt*16 + quad*4 + r
        float iv[4] = { gv[0], gv[1], gv[2], gv[3] };
        float fv[4] = { pv0, pv1, pv2, pv3 };
        float gg[4] = { qv0, qv1, qv2, qv3 };
        float ov[4] = { sv0, sv1, sv2, sv3 };
        float cc[4] = { c0, c1, c2, c3 };
        const int col = jbase + n;
        #pragma unroll
        for (int r = 0; r < 4; ++r){
          float cn = sigf(fv[r]) * cc[r] + sigf(iv[r]) * tanhf_(gg[r]);
          float hn = sigf(ov[r]) * tanhf_(cn);
          cc[r] = cn;
          const int b = mt * 16 + quad * 4 + r;
          unsigned pa = pk2(hn, 0.f);
          unsigned pd = pk2(hn, hn - lo16(pa));
          if (isL0){
            __hip_atomic_store(h1p + (size_t)(t & 1) * (BB * H0) + (size_t)b * H0 + col,
                               pd, __ATOMIC_RELAXED, __HIP_MEMORY_SCOPE_AGENT);
          } else {
            __hip_atomic_store(h2p + (size_t)(t & 1) * (BB * H1) + (size_t)b * H1 + col,
                               pd, __ATOMIC_RELAXED, __HIP_MEMORY_SCOPE_AGENT);
            // write-through so per-step L2 invalidates never see a dirty line
            __hip_atomic_store(out + ((size_t)b * TT + t) * H1 + col, hn,
                               __ATOMIC_RELAXED, __HIP_MEMORY_SCOPE_AGENT);
          }
        }
        c0 = cc[0]; c1 = cc[1]; c2 = cc[2]; c3 = cc[3];
      }
    }

    // ---- publish: barrier drains vmcnt (write-through stores are at the
    // coherence point once retired) -> per-WG relaxed flag store suffices ----
    __syncthreads();
    if (tid == 0){
      __hip_atomic_store(flg + wg, (unsigned)(i + 1),
                         __ATOMIC_RELAXED, __HIP_MEMORY_SCOPE_AGENT);
    }
  }
}

__global__ void init_ws(unsigned* ws, int nz){
  int i = blockIdx.x * blockDim.x + threadIdx.x;
  if (i < nz)
    __hip_atomic_store(ws + i, 0u, __ATOMIC_RELAXED, __HIP_MEMORY_SCOPE_AGENT);
}

__global__ void conv_x(const float4* __restrict__ x4,
                       unsigned long long* __restrict__ xp2, int n4){
  int i = blockIdx.x * blockDim.x + threadIdx.x;
  if (i >= n4) return;
  float4 f = x4[i];
  float v[4] = { f.x, f.y, f.z, f.w };
  unsigned o[4];
  #pragma unroll
  for (int d = 0; d < 4; ++d){
    unsigned p = pk2(v[d], 0.f);
    o[d] = pk2(v[d], v[d] - lo16(p));
  }
  unsigned long long lo = (unsigned long long)o[0] | ((unsigned long long)o[1] << 32);
  unsigned long long hi = (unsigned long long)o[2] | ((unsigned long long)o[3] << 32);
  // write-through: no dirty L2 lines to be lost by lstm_mfma's invalidates
  __hip_atomic_store(xp2 + 2 * i + 0, lo, __ATOMIC_RELAXED, __HIP_MEMORY_SCOPE_AGENT);
  __hip_atomic_store(xp2 + 2 * i + 1, hi, __ATOMIC_RELAXED, __HIP_MEMORY_SCOPE_AGENT);
}

extern "C" void kernel_launch(void* const* d_in, const int* in_sizes, int n_in,
                              void* d_out, int out_size, void* d_ws, size_t ws_size,
                              hipStream_t stream) {
  const float* x    = (const float*)d_in[0];
  const float* Wih0 = (const float*)d_in[1];
  const float* bih0 = (const float*)d_in[2];
  const float* Whh0 = (const float*)d_in[3];
  const float* bhh0 = (const float*)d_in[4];
  const float* Wih1 = (const float*)d_in[5];
  const float* bih1 = (const float*)d_in[6];
  const float* Whh1 = (const float*)d_in[7];
  const float* bhh1 = (const float*)d_in[8];
  float* outp = (float*)d_out;

  unsigned* ws   = (unsigned*)d_ws;
  unsigned* h1p  = ws;                       // 2*64*512  = 65536 dwords
  unsigned* h2p  = h1p + 2 * BB * H0;        // 2*64*256  = 32768
  unsigned* flg  = h2p + 2 * BB * H1;        // region sized 2*TT dwords (uses 192)
  unsigned* xp   = flg + 2 * TT;             // optional: B*T*DIN pair dwords
  const int nz = 2 * BB * H0 + 2 * BB * H1 + 2 * TT;   // dwords to zero

  const size_t need_xp = ((size_t)nz + (size_t)BB * TT * DIN) * 4;
  int use_xp = (ws_size >= need_xp) ? 1 : 0;

  init_ws<<<dim3((nz + 255) / 256), dim3(256), 0, stream>>>(ws, nz);
  if (use_xp){
    const int n4 = BB * TT * DIN / 4;
    conv_x<<<dim3((n4 + 255) / 256), dim3(256), 0, stream>>>(
        (const float4*)x, (unsigned long long*)xp, n4);
  }

  lstm_mfma<<<dim3(NWG), dim3(NTHR), 0, stream>>>(
      x, xp, use_xp,
      Wih0, bih0, Whh0, bhh0,
      Wih1, bih1, Whh1, bhh1,
      h1p, h2p, flg, outp);
}

// Round 3
// 9227.488 us; speedup vs baseline: 1.7038x; 1.1207x over previous
//
#include <hip/hip_runtime.h>

// ---------------------------------------------------------------------------
// V6: persistent MFMA LSTM — skewed pipeline + register-staged (batched) loads.
//  Same verified protocol as V5 (one global sync per iteration):
//    release: write-through h stores (sc0 sc1) -> __syncthreads vmcnt drain ->
//             per-WG relaxed flag store.
//    acquire: wave-0 polls 192 flags -> agent acquire fence (L1/L2 inv) ->
//             __syncthreads -> normal cached loads.
//  NEW: every load phase is register-staged — ALL global_load_dwordx4 of a
//  phase are issued back-to-back into explicit VGPR arrays before any
//  frag/MFMA consumes them.  V5's dependent load->mfma chains exposed
//  ~0.5us MALL-miss latency every few k-tiles (refill ran at 13 GB/s/XCD,
//  pure concurrency limit, 1 wave/SIMD -> no TLP).  Batching gives 32-48
//  outstanding loads per wave: refill cost ~= 1 latency + transfer.
// ---------------------------------------------------------------------------

constexpr int BB   = 64;
constexpr int TT   = 1024;
constexpr int DIN  = 256;
constexpr int H0   = 512;
constexpr int H1   = 256;
constexpr int NWG0 = 128;
constexpr int NWG1 = 64;
constexpr int NWG  = NWG0 + NWG1;
constexpr int NTHR = 256;
constexpr int NKT  = 24;       // K = 768 = 24 tiles of 32

typedef _Float16 v8h __attribute__((ext_vector_type(8)));
typedef __fp16   v2p __attribute__((ext_vector_type(2)));   // cvt_pkrtz result type
typedef float    v4f __attribute__((ext_vector_type(4)));
typedef unsigned int v4u __attribute__((ext_vector_type(4)));

union U1 { unsigned u; v2p h; };
union U4 { v4u u; v8h h; };

__device__ __forceinline__ unsigned pk2(float a, float b){
  U1 c; c.h = __builtin_amdgcn_cvt_pkrtz(a, b); return c.u;
}
__device__ __forceinline__ float lo16(unsigned u){ U1 c; c.u = u; return (float)c.h[0]; }
__device__ __forceinline__ float hi16(unsigned u){ U1 c; c.u = u; return (float)c.h[1]; }
__device__ __forceinline__ v8h as_h8(v4u u){ U4 c; c.u = u; return c.h; }

__device__ __forceinline__ v4f mfma16(v8h a, v8h b, v4f c){
  return __builtin_amdgcn_mfma_f32_16x16x32_f16(a, b, c, 0, 0, 0);
}

__device__ __forceinline__ float sigf(float v){ return 1.0f / (1.0f + __expf(-v)); }
__device__ __forceinline__ float tanhf_(float v){
  float e = __expf(2.0f * v);
  return 1.0f - 2.0f / (e + 1.0f);     // inf-safe
}

// wave-0 parallel flag wait: all flags[0..n) >= tgt (n multiple of 64).
__device__ __forceinline__ void waitflags(const unsigned* f, int n, unsigned tgt, int lane){
  for (;;){
    bool ok = true;
    #pragma unroll
    for (int base = 0; base < n; base += 64)
      ok = ok && (__hip_atomic_load(f + base + lane, __ATOMIC_RELAXED,
                                    __HIP_MEMORY_SCOPE_AGENT) >= tgt);
    if (__all(ok)) return;
    __builtin_amdgcn_s_sleep(1);
  }
}

// acquire at agent scope: s_waitcnt + invalidate L1/L2 so subsequent normal
// cached loads refill fresh data from the coherence point.
__device__ __forceinline__ void acq_fence(){
  __builtin_amdgcn_fence(__ATOMIC_ACQUIRE, "agent");
}

// pack two pair-dword quads into hi-plane / lo-plane A fragments
__device__ __forceinline__ void frag_from_pairs(v4u p0, v4u p1, v8h& A, v8h& B){
  v4u ua, ub;
  ua[0] = __builtin_amdgcn_perm(p0[1], p0[0], 0x05040100u);
  ua[1] = __builtin_amdgcn_perm(p0[3], p0[2], 0x05040100u);
  ua[2] = __builtin_amdgcn_perm(p1[1], p1[0], 0x05040100u);
  ua[3] = __builtin_amdgcn_perm(p1[3], p1[2], 0x05040100u);
  ub[0] = __builtin_amdgcn_perm(p0[1], p0[0], 0x07060302u);
  ub[1] = __builtin_amdgcn_perm(p0[3], p0[2], 0x07060302u);
  ub[2] = __builtin_amdgcn_perm(p1[1], p1[0], 0x07060302u);
  ub[3] = __builtin_amdgcn_perm(p1[3], p1[2], 0x07060302u);
  A = as_h8(ua); B = as_h8(ub);
}

__device__ __forceinline__ void frag_from_floats(v4f f0, v4f f1, v8h& A, v8h& B){
  float v[8] = { f0[0], f0[1], f0[2], f0[3], f1[0], f1[1], f1[2], f1[3] };
  v4u ua, ub;
  #pragma unroll
  for (int d = 0; d < 4; ++d){
    unsigned p = pk2(v[2*d], v[2*d+1]);
    ua[d] = p;
    ub[d] = pk2(v[2*d] - lo16(p), v[2*d+1] - hi16(p));
  }
  A = as_h8(ua); B = as_h8(ub);
}

__global__ void __launch_bounds__(NTHR, 1)
lstm_mfma(const float* __restrict__ x, const unsigned* __restrict__ xp, int use_xp,
          const float* __restrict__ Wih0, const float* __restrict__ bih0,
          const float* __restrict__ Whh0, const float* __restrict__ bhh0,
          const float* __restrict__ Wih1, const float* __restrict__ bih1,
          const float* __restrict__ Whh1, const float* __restrict__ bhh1,
          unsigned* h1p, unsigned* h2p,
          unsigned* flg, float* out)
{
  __shared__ v4u wfbs[NKT * 64];       // 24 KB: lo-plane weight B-fragments

  const int tid   = threadIdx.x;
  const int wg    = blockIdx.x;
  const bool isL0 = wg < NWG0;
  const int lw    = isL0 ? wg : wg - NWG0;
  const int H     = isL0 ? H0 : H1;
  const int jbase = lw * 4;            // 4 h-cols per WG
  const int lane  = tid & 63;
  const int mt    = tid >> 6;          // wave id = m-tile (16 batches)
  const int n     = lane & 15;         // MFMA n-index / A row-in-tile
  const int quad  = lane >> 4;
  // n -> gate (n>>2 in {i,f,g,o}), h-col jbase + (n&3)
  const int gcol  = (n >> 2) * H + jbase + (n & 3);
  const int brow  = mt * 16 + n;       // batch row this lane loads for A

  // ---- prologue: gather weight B-fragments; hi-plane -> VGPRs, lo -> LDS ----
  v4u wfa[NKT];
  {
    const float* Wi = isL0 ? Wih0 : Wih1;
    const float* Wh = isL0 ? Whh0 : Whh1;
    const int Ki  = isL0 ? DIN : H0;
    const int ldw = 4 * H;
    #pragma unroll
    for (int kt = 0; kt < NKT; ++kt){
      const int ks = kt * 32 + quad * 8;
      float w[8];
      #pragma unroll
      for (int j = 0; j < 8; ++j){
        const int k = ks + j;
        w[j] = (k < Ki) ? Wi[(size_t)k * ldw + gcol]
                        : Wh[(size_t)(k - Ki) * ldw + gcol];
      }
      v4u ua, ub;
      #pragma unroll
      for (int d = 0; d < 4; ++d){
        const unsigned p = pk2(w[2*d], w[2*d+1]);
        ua[d] = p;
        ub[d] = pk2(w[2*d] - lo16(p), w[2*d+1] - hi16(p));
      }
      wfa[kt] = ua;
      if (mt == 0) wfbs[kt * 64 + lane] = ub;   // fragments identical across waves
    }
  }
  const float bsum = isL0 ? (bih0[gcol] + bhh0[gcol]) : (bih1[gcol] + bhh1[gcol]);

  float c0 = 0.f, c1 = 0.f, c2 = 0.f, c3 = 0.f;   // cell state (lanes n<4)
  __syncthreads();

  // iteration i: L0 computes h1(i) (for i < TT); L1 computes h2(i-1) (i >= 1)
  for (int i = 0; i <= TT; ++i){
    const bool act = isL0 ? (i < TT) : (i >= 1);
    const int t    = isL0 ? i : (i - 1);          // this WG's time index

    v4f acc1 = { bsum, bsum, bsum, bsum };
    v4f acc2 = { 0.f, 0.f, 0.f, 0.f };

    // ---- L0 x-part: no cross-WG dependency, runs before the wait.
    //      Register-staged: all 16 loads issued before any compute. ----
    if (isL0 && act){
      if (use_xp){
        const unsigned* xr = xp + ((size_t)brow * TT + t) * DIN + quad * 8;
        v4u xP0[8], xP1[8];
        #pragma unroll
        for (int kt = 0; kt < 8; ++kt){
          xP0[kt] = *(const v4u*)(xr + kt * 32);
          xP1[kt] = *(const v4u*)(xr + kt * 32 + 4);
        }
        #pragma unroll
        for (int kt = 0; kt < 8; ++kt){
          v8h A, Ab; frag_from_pairs(xP0[kt], xP1[kt], A, Ab);
          v8h Wa = as_h8(wfa[kt]), Wb = as_h8(wfbs[kt * 64 + lane]);
          acc1 = mfma16(A,  Wa, acc1);
          acc2 = mfma16(A,  Wb, acc2);
          acc2 = mfma16(Ab, Wa, acc2);
        }
      } else {
        const float* xr = x + ((size_t)brow * TT + t) * DIN + quad * 8;
        v4f xF0[8], xF1[8];
        #pragma unroll
        for (int kt = 0; kt < 8; ++kt){
          xF0[kt] = *(const v4f*)(xr + kt * 32);
          xF1[kt] = *(const v4f*)(xr + kt * 32 + 4);
        }
        #pragma unroll
        for (int kt = 0; kt < 8; ++kt){
          v8h A, Ab; frag_from_floats(xF0[kt], xF1[kt], A, Ab);
          v8h Wa = as_h8(wfa[kt]), Wb = as_h8(wfbs[kt * 64 + lane]);
          acc1 = mfma16(A,  Wa, acc1);
          acc2 = mfma16(A,  Wb, acc2);
          acc2 = mfma16(Ab, Wa, acc2);
        }
      }
    }

    // ---- the single global sync: all WGs finished iteration i-1 ----
    if (tid < 64){
      if (i >= 1) waitflags(flg, NWG, (unsigned)i, lane);
      acq_fence();          // unconditional: also guards graph-replay staleness
    }
    __syncthreads();

    if (act){
      if (isL0){
        // ---- h1(t-1) part, slot (t+1)&1: 32 loads issued, then compute ----
        const unsigned* hr = h1p + (size_t)((t + 1) & 1) * (BB * H0)
                                 + (size_t)brow * H0 + quad * 8;
        v4u hP0[16], hP1[16];
        #pragma unroll
        for (int kt = 0; kt < 16; ++kt){
          hP0[kt] = *(const v4u*)(hr + kt * 32);
          hP1[kt] = *(const v4u*)(hr + kt * 32 + 4);
        }
        #pragma unroll
        for (int kt = 0; kt < 16; ++kt){
          v8h A, Ab; frag_from_pairs(hP0[kt], hP1[kt], A, Ab);
          v8h Wa = as_h8(wfa[kt + 8]), Wb = as_h8(wfbs[(kt + 8) * 64 + lane]);
          acc1 = mfma16(A,  Wa, acc1);
          acc2 = mfma16(A,  Wb, acc2);
          acc2 = mfma16(Ab, Wa, acc2);
        }
      } else {
        // ---- L1: issue h2(t-1) loads (16) AND h1(t) loads (32) back-to-back,
        //      then compute h2 part, then h1 part ----
        const unsigned* h2r = h2p + (size_t)((t + 1) & 1) * (BB * H1)
                                  + (size_t)brow * H1 + quad * 8;
        const unsigned* hr  = h1p + (size_t)(t & 1) * (BB * H0)
                                  + (size_t)brow * H0 + quad * 8;
        v4u aP0[8], aP1[8];
        #pragma unroll
        for (int kt = 0; kt < 8; ++kt){
          aP0[kt] = *(const v4u*)(h2r + kt * 32);
          aP1[kt] = *(const v4u*)(h2r + kt * 32 + 4);
        }
        v4u bP0[16], bP1[16];
        #pragma unroll
        for (int kt = 0; kt < 16; ++kt){
          bP0[kt] = *(const v4u*)(hr + kt * 32);
          bP1[kt] = *(const v4u*)(hr + kt * 32 + 4);
        }
        #pragma unroll
        for (int kt = 0; kt < 8; ++kt){
          v8h A, Ab; frag_from_pairs(aP0[kt], aP1[kt], A, Ab);
          v8h Wa = as_h8(wfa[kt + 16]), Wb = as_h8(wfbs[(kt + 16) * 64 + lane]);
          acc1 = mfma16(A,  Wa, acc1);
          acc2 = mfma16(A,  Wb, acc2);
          acc2 = mfma16(Ab, Wa, acc2);
        }
        #pragma unroll
        for (int kt = 0; kt < 16; ++kt){
          v8h A, Ab; frag_from_pairs(bP0[kt], bP1[kt], A, Ab);
          v8h Wa = as_h8(wfa[kt]), Wb = as_h8(wfbs[kt * 64 + lane]);
          acc1 = mfma16(A,  Wa, acc1);
          acc2 = mfma16(A,  Wb, acc2);
          acc2 = mfma16(Ab, Wa, acc2);
        }
      }

      // ---- elementwise LSTM: gather (i,f,g,o) per (b, h-col) via shfl_xor ----
      v4f gv = acc1 + acc2;
      float pv0 = __shfl_xor(gv[0], 4), pv1 = __shfl_xor(gv[1], 4),
            pv2 = __shfl_xor(gv[2], 4), pv3 = __shfl_xor(gv[3], 4);
      float qv0 = __shfl_xor(gv[0], 8), qv1 = __shfl_xor(gv[1], 8),
            qv2 = __shfl_xor(gv[2], 8), qv3 = __shfl_xor(gv[3], 8);
      float sv0 = __shfl_xor(pv0, 8), sv1 = __shfl_xor(pv1, 8),
            sv2 = __shfl_xor(pv2, 8), sv3 = __shfl_xor(pv3, 8);

      if (n < 4){
        // lane n<4: i = gv, f = pv, g = qv, o = sv ; rows b = mt*16 + quad*4 + r
        float iv[4] = { gv[0], gv[1], gv[2], gv[3] };
        float fv[4] = { pv0, pv1, pv2, pv3 };
        float gg[4] = { qv0, qv1, qv2, qv3 };
        float ov[4] = { sv0, sv1, sv2, sv3 };
        float cc[4] = { c0, c1, c2, c3 };
        const int col = jbase + n;
        #pragma unroll
        for (int r = 0; r < 4; ++r){
          float cn = sigf(fv[r]) * cc[r] + sigf(iv[r]) * tanhf_(gg[r]);
          float hn = sigf(ov[r]) * tanhf_(cn);
          cc[r] = cn;
          const int b = mt * 16 + quad * 4 + r;
          unsigned pa = pk2(hn, 0.f);
          unsigned pd = pk2(hn, hn - lo16(pa));
          if (isL0){
            __hip_atomic_store(h1p + (size_t)(t & 1) * (BB * H0) + (size_t)b * H0 + col,
                               pd, __ATOMIC_RELAXED, __HIP_MEMORY_SCOPE_AGENT);
          } else {
            __hip_atomic_store(h2p + (size_t)(t & 1) * (BB * H1) + (size_t)b * H1 + col,
                               pd, __ATOMIC_RELAXED, __HIP_MEMORY_SCOPE_AGENT);
            // write-through so per-step L2 invalidates never see a dirty line
            __hip_atomic_store(out + ((size_t)b * TT + t) * H1 + col, hn,
                               __ATOMIC_RELAXED, __HIP_MEMORY_SCOPE_AGENT);
          }
        }
        c0 = cc[0]; c1 = cc[1]; c2 = cc[2]; c3 = cc[3];
      }
    }

    // ---- publish: barrier drains vmcnt (write-through stores are at the
    // coherence point once retired) -> per-WG relaxed flag store suffices ----
    __syncthreads();
    if (tid == 0){
      __hip_atomic_store(flg + wg, (unsigned)(i + 1),
                         __ATOMIC_RELAXED, __HIP_MEMORY_SCOPE_AGENT);
    }
  }
}

__global__ void init_ws(unsigned* ws, int nz){
  int i = blockIdx.x * blockDim.x + threadIdx.x;
  if (i < nz)
    __hip_atomic_store(ws + i, 0u, __ATOMIC_RELAXED, __HIP_MEMORY_SCOPE_AGENT);
}

__global__ void conv_x(const float4* __restrict__ x4,
                       unsigned long long* __restrict__ xp2, int n4){
  int i = blockIdx.x * blockDim.x + threadIdx.x;
  if (i >= n4) return;
  float4 f = x4[i];
  float v[4] = { f.x, f.y, f.z, f.w };
  unsigned o[4];
  #pragma unroll
  for (int d = 0; d < 4; ++d){
    unsigned p = pk2(v[d], 0.f);
    o[d] = pk2(v[d], v[d] - lo16(p));
  }
  unsigned long long lo = (unsigned long long)o[0] | ((unsigned long long)o[1] << 32);
  unsigned long long hi = (unsigned long long)o[2] | ((unsigned long long)o[3] << 32);
  // write-through: no dirty L2 lines to be lost by lstm_mfma's invalidates
  __hip_atomic_store(xp2 + 2 * i + 0, lo, __ATOMIC_RELAXED, __HIP_MEMORY_SCOPE_AGENT);
  __hip_atomic_store(xp2 + 2 * i + 1, hi, __ATOMIC_RELAXED, __HIP_MEMORY_SCOPE_AGENT);
}

extern "C" void kernel_launch(void* const* d_in, const int* in_sizes, int n_in,
                              void* d_out, int out_size, void* d_ws, size_t ws_size,
                              hipStream_t stream) {
  const float* x    = (const float*)d_in[0];
  const float* Wih0 = (const float*)d_in[1];
  const float* bih0 = (const float*)d_in[2];
  const float* Whh0 = (const float*)d_in[3];
  const float* bhh0 = (const float*)d_in[4];
  const float* Wih1 = (const float*)d_in[5];
  const float* bih1 = (const float*)d_in[6];
  const float* Whh1 = (const float*)d_in[7];
  const float* bhh1 = (const float*)d_in[8];
  float* outp = (float*)d_out;

  unsigned* ws   = (unsigned*)d_ws;
  unsigned* h1p  = ws;                       // 2*64*512  = 65536 dwords
  unsigned* h2p  = h1p + 2 * BB * H0;        // 2*64*256  = 32768
  unsigned* flg  = h2p + 2 * BB * H1;        // region sized 2*TT dwords (uses 192)
  unsigned* xp   = flg + 2 * TT;             // optional: B*T*DIN pair dwords
  const int nz = 2 * BB * H0 + 2 * BB * H1 + 2 * TT;   // dwords to zero

  const size_t need_xp = ((size_t)nz + (size_t)BB * TT * DIN) * 4;
  int use_xp = (ws_size >= need_xp) ? 1 : 0;

  init_ws<<<dim3((nz + 255) / 256), dim3(256), 0, stream>>>(ws, nz);
  if (use_xp){
    const int n4 = BB * TT * DIN / 4;
    conv_x<<<dim3((n4 + 255) / 256), dim3(256), 0, stream>>>(
        (const float4*)x, (unsigned long long*)xp, n4);
  }

  lstm_mfma<<<dim3(NWG), dim3(NTHR), 0, stream>>>(
      x, xp, use_xp,
      Wih0, bih0, Whh0, bhh0,
      Wih1, bih1, Whh1, bhh1,
      h1p, h2p, flg, outp);
}